// Round 2
// baseline (80.063 us; speedup 1.0000x reference)
//
#include <hip/hip_runtime.h>

#define V 96
#define VV (V * V)
#define V3 (V * V * V)
#define B_ 4
#define N_ 32
#define P_ 32
#define TILE 64                   // pixels per block (one per lane)
#define TPB 256
#define SPLITS 4                  // waves per block = polygon-split factor
#define TILES_PER_B (VV / TILE)   // 144

// Broadcast a float from lane l (compile-time constant in the unrolled loop).
// v_readlane_b32: register-file read, no LDS pipe, no memory latency.
__device__ __forceinline__ float rl(float x, int l) {
    return __uint_as_float(__builtin_amdgcn_readlane(__float_as_uint(x), l));
}

// One fused kernel: polygon masks (max over valid polys) + depth extrusion.
// Block = 256 threads = 4 waves; each block owns 64 consecutive pixels of one
// batch element; wave s handles valid polygons j = s, s+4, ...
// Edge data lives in per-lane registers (lane p owns edge p) and is broadcast
// via v_readlane — the inner loop touches no memory at all.
__global__ __launch_bounds__(TPB) void fused_kernel(
    const float* __restrict__ poly,      // (B,N,P,2)
    const float* __restrict__ attr,      // (B,8)
    const float* __restrict__ validity,  // (B,N)
    float4* __restrict__ out)            // (B,V,V,V) viewed as float4
{
    __shared__ float spart[SPLITS][TILE];
    __shared__ __align__(16) float sfinal[TILE];
    __shared__ int svalidIdx[N_];
    __shared__ int scnt;

    const int b       = blockIdx.x / TILES_PER_B;
    const int tileInB = blockIdx.x - b * TILES_PER_B;
    const int pix0    = tileInB * TILE;
    const int tid     = threadIdx.x;
    const int s       = tid >> 6;            // wave id = polygon split
    const int lane    = tid & 63;

    // wave 0: compact the valid-polygon list via ballot
    if (tid < 64) {
        bool v = (tid < N_) && (validity[b * N_ + tid] >= 0.5f);
        unsigned long long m = __ballot(v);
        if (v) {
            int pos = __popcll(m & ((1ull << tid) - 1));
            svalidIdx[pos] = tid;
        }
        if (tid == 0) scnt = (int)__popcll(m);
    }
    __syncthreads();

    // this thread's pixel, exact fp32 coords (match numpy)
    const int pixel = pix0 + lane;
    const int py_i  = pixel / V;
    const int px_i  = pixel - py_i * V;
    const float px = (float)px_i / 95.0f;
    const float py = (float)py_i / 95.0f;

    const int cnt = scnt;
    const int p_  = lane & (P_ - 1);         // edge owned by this lane
    const float2* f2base = (const float2*)poly + (size_t)b * (N_ * P_);

    float pmax = 0.0f;

    for (int j = s; j < cnt; j += SPLITS) {
        const int nidx = svalidIdx[j];
        // per-lane edge struct for edge p_ of polygon nidx (lanes 32-63 mirror 0-31)
        const float2* f2 = f2base + nidx * P_;
        float2 v0 = f2[p_];
        float2 v1 = f2[(p_ + 1) & (P_ - 1)];
        float aex = v1.x - v0.x;
        float aey = v1.y - v0.y;
        float arq = __builtin_amdgcn_rcpf(aex * aex + aey * aey + 1e-8f);
        float ary = __builtin_amdgcn_rcpf(aey + 1e-8f);
        float ax0 = v0.x, ay0 = v0.y, ay1 = v1.y;

        float mind2 = 1e30f;
        int par = 0;
        #pragma unroll
        for (int p = 0; p < P_; ++p) {
            // broadcast edge p's values from lane p — pure register traffic
            float x0 = rl(ax0, p);
            float y0 = rl(ay0, p);
            float ex = rl(aex, p);
            float ey = rl(aey, p);
            float rq = rl(arq, p);
            float ry = rl(ary, p);
            float y1 = rl(ay1, p);
            // point-to-segment squared distance
            float vx = px - x0, vy = py - y0;
            float t  = (vx * ex + vy * ey) * rq;
            t = fminf(fmaxf(t, 0.0f), 1.0f);
            float dx = vx - t * ex, dy = vy - t * ey;
            float d2 = dx * dx + dy * dy;
            mind2 = fminf(mind2, d2);
            // even-odd crossing test (exact y1 from vertex)
            bool c0 = (y0 <= py);
            bool c1 = (y1 <= py);
            float inter_x = x0 + ex * (vy * ry);
            par ^= (int)((c0 != c1) & (inter_x > px));
        }
        float mind = sqrtf(mind2);
        float sdf  = par ? -mind : mind;
        // sigmoid(-sdf*100) = 1/(1+exp(100*sdf))
        float m = 1.0f / (1.0f + __expf(sdf * 100.0f));
        pmax = fmaxf(pmax, m);
    }

    spart[s][lane] = pmax;
    __syncthreads();
    float f = fmaxf(fmaxf(spart[0][lane], spart[1][lane]),
                    fmaxf(spart[2][lane], spart[3][lane]));
    if (s == 0) sfinal[lane] = f;
    __syncthreads();

    // ---- write phase: 96 depth slices of this 64-pixel tile ----
    float a  = attr[b * 8];
    float nh = fminf(fmaxf(a, 0.0f), 1.0f);
    float hv = fminf(fmaxf(rintf(nh * (float)V), 1.0f), (float)V); // rintf = numpy half-even
    int hvi = (int)hv;

    const float4* sf4 = (const float4*)sfinal;
    const float4 val = sf4[lane & 15];
    size_t obase = (size_t)b * (V3 / 4) + (size_t)(pix0 >> 2) + (lane & 15);
    #pragma unroll
    for (int k = 0; k < 6; ++k) {
        int d = s * 24 + k * 4 + (lane >> 4);        // covers d = 0..95 exactly once
        float keep = (d < hvi) ? 1.0f : 0.0f;
        out[obase + (size_t)d * (VV / 4)] =
            make_float4(val.x * keep, val.y * keep, val.z * keep, val.w * keep);
    }
}

extern "C" void kernel_launch(void* const* d_in, const int* in_sizes, int n_in,
                              void* d_out, int out_size, void* d_ws, size_t ws_size,
                              hipStream_t stream) {
    const float* polygons = (const float*)d_in[0];   // (4,32,32,2)
    const float* attrs    = (const float*)d_in[1];   // (4,8)
    const float* validity = (const float*)d_in[2];   // (4,32)
    float4* out = (float4*)d_out;                    // (4,96,96,96)

    // single fused dispatch: no workspace use, no memset, no atomics
    fused_kernel<<<B_ * TILES_PER_B, TPB, 0, stream>>>(polygons, attrs, validity, out);
}

// Round 3
// 74.312 us; speedup vs baseline: 1.0774x; 1.0774x over previous
//
#include <hip/hip_runtime.h>

#define V 96
#define VV (V * V)
#define V3 (V * V * V)
#define B_ 4
#define N_ 32
#define P_ 32
#define NE (N_ * P_)              // 1024 edges per batch element
#define TILE 64                   // pixels per block (one per lane)
#define TPB 512
#define NW (TPB / 64)             // 8 waves = poly-split factor
#define TILES_PER_B (VV / TILE)   // 144

// One fused kernel: polygon masks (max over valid polys) + depth extrusion.
// Block = 512 threads = 8 waves; each block owns 64 consecutive pixels of one
// batch element; wave s handles valid polygons j = s, s+8, ... (~2 each).
// Edge structs live in LDS as float4 pairs; inner-loop reads are wave-uniform
// broadcasts (no bank conflicts). Unroll capped at 8 to bound VGPR pressure.
__global__ __launch_bounds__(TPB) void fused_kernel(
    const float* __restrict__ poly,      // (B,N,P,2)
    const float* __restrict__ attr,      // (B,8)
    const float* __restrict__ validity,  // (B,N)
    float4* __restrict__ out)            // (B,V,V,V) viewed as float4
{
    __shared__ float4 se0[NE];               // {x0, y0, ex, ey}      16 KB
    __shared__ float4 se1[NE];               // {rq, ry, y1, 0}       16 KB
    __shared__ float2 sraw[NE];              // raw vertices           8 KB
    __shared__ float  spart[NW][TILE];       // per-wave partial max   2 KB
    __shared__ __align__(16) float sfinal[TILE];
    __shared__ int svalidIdx[N_];
    __shared__ int scnt;

    const int b       = blockIdx.x / TILES_PER_B;
    const int tileInB = blockIdx.x - b * TILES_PER_B;
    const int pix0    = tileInB * TILE;
    const int tid     = threadIdx.x;
    const int s       = tid >> 6;            // wave id = polygon split
    const int lane    = tid & 63;

    // ---- stage this b's 1024 raw vertices (one float4 = 2 vertices/thread)
    {
        const float4* pg = (const float4*)(poly + (size_t)b * (NE * 2));
        ((float4*)sraw)[tid] = pg[tid];
    }
    // wave 0: compact the valid-polygon list via ballot
    if (tid < 64) {
        bool v = (tid < N_) && (validity[b * N_ + tid] >= 0.5f);
        unsigned long long m = __ballot(v);
        if (v) svalidIdx[__popcll(m & ((1ull << tid) - 1))] = tid;
        if (tid == 0) scnt = (int)__popcll(m);
    }
    __syncthreads();

    // ---- build edge structs (2 edges per thread) ----
    #pragma unroll
    for (int i = 0; i < 2; ++i) {
        int e  = tid + i * TPB;
        int p  = e & (P_ - 1);
        int en = (e & ~(P_ - 1)) | ((p + 1) & (P_ - 1));  // wrap within polygon
        float2 v0 = sraw[e];
        float2 v1 = sraw[en];
        float ex = v1.x - v0.x, ey = v1.y - v0.y;
        se0[e] = make_float4(v0.x, v0.y, ex, ey);
        se1[e] = make_float4(__builtin_amdgcn_rcpf(ex * ex + ey * ey + 1e-8f),
                             __builtin_amdgcn_rcpf(ey + 1e-8f),
                             v1.y,            // exact vertex y for crossing test
                             0.0f);
    }
    __syncthreads();

    // ---- compute phase: this thread's pixel, exact fp32 coords (match numpy)
    const int pixel = pix0 + lane;
    const int py_i  = pixel / V;
    const int px_i  = pixel - py_i * V;
    const float px = (float)px_i / 95.0f;
    const float py = (float)py_i / 95.0f;

    const int cnt = scnt;
    float pmax = 0.0f;

    for (int j = s; j < cnt; j += NW) {
        const int base = svalidIdx[j] << 5;   // n * 32
        float mind2 = 1e30f;
        int par = 0;
        #pragma unroll 8
        for (int p = 0; p < P_; ++p) {
            float4 e0 = se0[base + p];        // wave-uniform broadcast b128
            float4 e1 = se1[base + p];
            // point-to-segment squared distance
            float vx = px - e0.x, vy = py - e0.y;
            float t  = (vx * e0.z + vy * e0.w) * e1.x;
            t = fminf(fmaxf(t, 0.0f), 1.0f);
            float dx = vx - t * e0.z, dy = vy - t * e0.w;
            mind2 = fminf(mind2, dx * dx + dy * dy);
            // even-odd crossing test (exact y1 from vertex)
            bool c0 = (e0.y <= py);
            bool c1 = (e1.z <= py);
            float ix = e0.x + e0.z * (vy * e1.y);
            par ^= (int)((c0 != c1) & (ix > px));
        }
        float mind = sqrtf(mind2);
        float sdf  = par ? -mind : mind;
        // sigmoid(-sdf*100) = 1/(1+exp(100*sdf))
        float m = 1.0f / (1.0f + __expf(sdf * 100.0f));
        pmax = fmaxf(pmax, m);
    }

    spart[s][lane] = pmax;
    __syncthreads();
    if (tid < 64) {
        float f = spart[0][lane];
        #pragma unroll
        for (int w = 1; w < NW; ++w) f = fmaxf(f, spart[w][lane]);
        sfinal[lane] = f;
    }
    __syncthreads();

    // ---- write phase: 96 depth slices x 64 pixels = 1536 float4, 3/thread
    float a  = attr[b * 8];
    float nh = fminf(fmaxf(a, 0.0f), 1.0f);
    float hv = fminf(fmaxf(rintf(nh * (float)V), 1.0f), (float)V); // rintf = numpy half-even
    int hvi = (int)hv;

    const float4* sf4 = (const float4*)sfinal;
    size_t obase = (size_t)b * (V3 / 4) + (size_t)(pix0 >> 2);
    #pragma unroll
    for (int k = 0; k < 3; ++k) {
        int idx = k * TPB + tid;             // 0..1535
        int d   = idx >> 4;                  // depth slice 0..95
        int x4  = idx & 15;                  // float4 within the 64-px tile
        float4 val = sf4[x4];
        float keep = (d < hvi) ? 1.0f : 0.0f;
        out[obase + (size_t)d * (VV / 4) + x4] =
            make_float4(val.x * keep, val.y * keep, val.z * keep, val.w * keep);
    }
}

extern "C" void kernel_launch(void* const* d_in, const int* in_sizes, int n_in,
                              void* d_out, int out_size, void* d_ws, size_t ws_size,
                              hipStream_t stream) {
    const float* polygons = (const float*)d_in[0];   // (4,32,32,2)
    const float* attrs    = (const float*)d_in[1];   // (4,8)
    const float* validity = (const float*)d_in[2];   // (4,32)
    float4* out = (float4*)d_out;                    // (4,96,96,96)

    // single fused dispatch: no workspace use, no memset, no atomics
    fused_kernel<<<B_ * TILES_PER_B, TPB, 0, stream>>>(polygons, attrs, validity, out);
}